// Round 1
// 288.841 us; speedup vs baseline: 1.0554x; 1.0554x over previous
//
#include <hip/hip_runtime.h>
#include <hip/hip_fp16.h>
#include <math.h>

#define N_NODES 50000
#define N_EDGES 800000
#define NEG_SLOPE 0.2f

#define BKT_SHIFT 7
#define N_BKT 512                      // pow2 upper bound; used: ceil(50000/128)=391
#define NB_CSR ((N_NODES + 127) / 128) // 391
#define CHUNK 2048                     // edges per phase-A block
#define BCAP 4096                      // fixed bucket capacity (mean 2048, 45 sigma)
#define PB_CAP 4096
#define G1_BLOCKS (((N_NODES + 127) / 128) * 2)   // 782 gemm-1 blocks (2 n-tiles)

typedef _Float16 v8h __attribute__((ext_vector_type(8)));
typedef _Float16 h4  __attribute__((ext_vector_type(4)));
typedef _Float16 h2  __attribute__((ext_vector_type(2)));
typedef float f32x4 __attribute__((ext_vector_type(4)));
typedef float f32x2 __attribute__((ext_vector_type(2)));

static inline int cdiv(long long a, int b) { return (int)((a + b - 1) / b); }

// ========= weight packing W[K][N] f32 -> Wt[N][K] f16, plus bcnt zero-init =========
__global__ void pack_weights_zero(const float* __restrict__ W1l, const float* __restrict__ W1r,
                                  const float* __restrict__ W2l, const float* __restrict__ W2r,
                                  const float* __restrict__ W3l, const float* __restrict__ W3r,
                                  _Float16* __restrict__ Wt1, _Float16* __restrict__ Wt2,
                                  _Float16* __restrict__ Wt3, int* __restrict__ bcnt) {
    int id = blockIdx.x * blockDim.x + threadIdx.x;
    if (id < 32768) {                       // Wt1: [256][128]
        int n = id >> 7, k = id & 127;
        Wt1[id] = (_Float16)(n < 128 ? W1l[k * 128 + n] : W1r[k * 128 + n - 128]);
    } else if (id < 65536) {                // Wt2: [256][128]
        int j = id - 32768; int n = j >> 7, k = j & 127;
        Wt2[j] = (_Float16)(n < 128 ? W2l[k * 128 + n] : W2r[k * 128 + n - 128]);
    } else if (id < 81920) {                // Wt3: [128][128]
        int j = id - 65536; int n = j >> 7, k = j & 127;
        Wt3[j] = (_Float16)(n < 64 ? W3l[k * 64 + n] : W3r[k * 64 + n - 64]);
    } else if (id < 81920 + N_BKT) {
        bcnt[id - 81920] = 0;
    }
}

// ===== Phase A: LDS bucket sort per 2048-edge chunk, coalesced run append =====
__global__ __launch_bounds__(512) void bucket_scatter(const int* __restrict__ esrc,
                                                      const int* __restrict__ edst,
                                                      int* __restrict__ bcnt,
                                                      int2* __restrict__ tmp) {
    __shared__ int lhist[N_BKT];
    __shared__ int lscan[N_BKT];
    __shared__ int lofs[N_BKT];
    __shared__ int lcur[N_BKT];
    __shared__ int gbase[N_BKT];
    __shared__ int2 lpair[CHUNK];
    int tid = threadIdx.x;
    int base_e = blockIdx.x * CHUNK;
    int count = min(CHUNK, N_EDGES - base_e);

    if (tid < N_BKT) lhist[tid] = 0;
    __syncthreads();

    int e0 = base_e + tid * 4;
    int4 s4 = {0, 0, 0, 0}, d4 = {0, 0, 0, 0};
    int nmine = 0;
    if (e0 + 3 < N_EDGES && e0 + 3 < base_e + count) {
        s4 = *(const int4*)(esrc + e0);
        d4 = *(const int4*)(edst + e0);
        nmine = 4;
    } else if (e0 < N_EDGES) {
        nmine = min(N_EDGES - e0, 4);
        const int* sp = esrc + e0;
        const int* dp = edst + e0;
        if (nmine > 0) { s4.x = sp[0]; d4.x = dp[0]; }
        if (nmine > 1) { s4.y = sp[1]; d4.y = dp[1]; }
        if (nmine > 2) { s4.z = sp[2]; d4.z = dp[2]; }
    }
    int ds[4] = {d4.x, d4.y, d4.z, d4.w};
    int ss[4] = {s4.x, s4.y, s4.z, s4.w};
#pragma unroll
    for (int u = 0; u < 4; ++u)
        if (u < nmine) atomicAdd(&lhist[ds[u] >> BKT_SHIFT], 1);
    __syncthreads();

    // exclusive scan over N_BKT in LDS (Hillis-Steele, 512 threads = N_BKT)
    int v = lhist[tid];
    lscan[tid] = v;
    __syncthreads();
    for (int st = 1; st < N_BKT; st <<= 1) {
        int t = (tid >= st) ? lscan[tid - st] : 0;
        __syncthreads();
        lscan[tid] += t;
        __syncthreads();
    }
    {
        int excl = lscan[tid] - v;
        lofs[tid] = excl;
        lcur[tid] = excl;
        if (v > 0) gbase[tid] = tid * BCAP + atomicAdd(&bcnt[tid], v);
    }
    __syncthreads();

#pragma unroll
    for (int u = 0; u < 4; ++u)
        if (u < nmine) {
            int b = ds[u] >> BKT_SHIFT;
            int p = atomicAdd(&lcur[b], 1);
            lpair[p] = make_int2(ss[u], ds[u]);
        }
    __syncthreads();

    for (int j = tid; j < count; j += 512) {
        int2 pr = lpair[j];
        int b = pr.y >> BKT_SHIFT;
        int idx = gbase[b] + (j - lofs[b]);
        if (idx < (b + 1) * BCAP) tmp[idx] = pr;   // 45-sigma overflow guard
    }
}

// ===== Merged dispatch: blocks [0,391) finalize CSR; blocks [391, 391+782) run layer-1 GEMM =====
// Independent work items; both complete before fused_gat layer 1. Saves a launch gap and
// overlaps csr LDS-ranking with MFMA.
// R15: n-tile (by) is now the FASTEST-varying coordinate of gb so both n-tiles of a given
// bx run temporally adjacent -> the f32 A rows (25.6MB) are read once from HBM, second
// read hits L2/L3.
__global__ __launch_bounds__(256, 2) void csr_and_gemm1(const int* __restrict__ bcnt,
                                                        const int2* __restrict__ tmp,
                                                        int* __restrict__ off,
                                                        int* __restrict__ csr,
                                                        const float* __restrict__ A,
                                                        const _Float16* __restrict__ Bt,
                                                        _Float16* __restrict__ C) {
    __shared__ int red[256];
    __shared__ int lcnt[128];
    __shared__ int sc[128];
    __shared__ int loff[129];
    __shared__ int lcur[128];
    __shared__ int lcsr[PB_CAP];
    int tid = threadIdx.x;

    if (blockIdx.x >= NB_CSR) {
        // ---------------- layer-1 GEMM part (A = f32 input, cast in-register) ------------
        int gb = blockIdx.x - NB_CSR;
        int bx = gb >> 1;               // R15: by fastest for A-row temporal reuse
        int by = gb & 1;                // 0 or 1
        int w = tid >> 6, lane = tid & 63;
        int m0 = bx * 128 + (w & 1) * 64;
        int n0 = by * 128 + (w >> 1) * 64;
        int q = lane >> 4, li = lane & 15;
        f32x4 acc[4][4] = {};
        const float* Ap[4];
#pragma unroll
        for (int a = 0; a < 4; ++a) {
            int row = m0 + 16 * a + li;
            if (row > N_NODES - 1) row = N_NODES - 1;
            Ap[a] = A + (size_t)row * 128 + q * 8;
        }
        const _Float16* Bp = Bt + (size_t)(n0 + li) * 128 + q * 8;
#pragma unroll
        for (int kt = 0; kt < 4; ++kt) {
            v8h af[4], bf[4];
#pragma unroll
            for (int a = 0; a < 4; ++a) {
                float4 lo = *(const float4*)(Ap[a] + kt * 32);
                float4 hi = *(const float4*)(Ap[a] + kt * 32 + 4);
                v8h t;
                t[0] = (_Float16)lo.x; t[1] = (_Float16)lo.y; t[2] = (_Float16)lo.z; t[3] = (_Float16)lo.w;
                t[4] = (_Float16)hi.x; t[5] = (_Float16)hi.y; t[6] = (_Float16)hi.z; t[7] = (_Float16)hi.w;
                af[a] = t;
            }
#pragma unroll
            for (int b = 0; b < 4; ++b) bf[b] = *(const v8h*)(Bp + (size_t)(16 * b) * 128 + kt * 32);
#pragma unroll
            for (int a = 0; a < 4; ++a)
#pragma unroll
                for (int b = 0; b < 4; ++b)
                    acc[a][b] = __builtin_amdgcn_mfma_f32_16x16x32_f16(bf[b], af[a], acc[a][b], 0, 0, 0);
        }
#pragma unroll
        for (int a = 0; a < 4; ++a) {
            int m = m0 + 16 * a + li;
            if (m < N_NODES) {
#pragma unroll
                for (int b = 0; b < 4; ++b) {
                    h4 t;
                    t[0] = (_Float16)acc[a][b][0]; t[1] = (_Float16)acc[a][b][1];
                    t[2] = (_Float16)acc[a][b][2]; t[3] = (_Float16)acc[a][b][3];
                    *(h4*)(C + (size_t)m * 256 + n0 + 16 * b + 4 * q) = t;
                }
            }
        }
        return;
    }

    // ---------------- CSR finalize part ----------------
    int b = blockIdx.x;
    int d0 = b << BKT_SHIFT;
    int dend = min(d0 + 128, N_NODES);
    int nn = dend - d0;

    int pre = 0;
    for (int i = tid; i < b; i += 256) pre += bcnt[i];
    red[tid] = pre;
    __syncthreads();
    for (int st = 128; st > 0; st >>= 1) {
        if (tid < st) red[tid] += red[tid + st];
        __syncthreads();
    }
    int base = red[0];
    __syncthreads();

    int n = min(bcnt[b], BCAP);
    int tbase = b * BCAP;

    if (tid < 128) lcnt[tid] = 0;
    __syncthreads();
    for (int j = tid; j < n; j += 256) {
        int dl = tmp[tbase + j].y - d0;
        atomicAdd(&lcnt[dl], 1);
    }
    __syncthreads();

    if (tid < 128) sc[tid] = lcnt[tid];
    __syncthreads();
    for (int st = 1; st < 128; st <<= 1) {
        int t = (tid < 128 && tid >= st) ? sc[tid - st] : 0;
        __syncthreads();
        if (tid < 128) sc[tid] += t;
        __syncthreads();
    }
    if (tid < 128) loff[tid + 1] = sc[tid];
    if (tid == 0) loff[0] = 0;
    if (tid < 128) lcur[tid] = 0;
    __syncthreads();

    if (tid < nn) off[d0 + tid] = base + loff[tid];
    if (tid == 0 && dend == N_NODES) off[N_NODES] = base + loff[nn];

    for (int j = tid; j < n; j += 256) {
        int2 pr = tmp[tbase + j];
        int dl = pr.y - d0;
        int r = atomicAdd(&lcur[dl], 1);
        int pos = loff[dl] + r;
        if (pos < PB_CAP) lcsr[pos] = pr.x;
    }
    __syncthreads();
    for (int j = tid; j < n; j += 256) csr[base + j] = lcsr[j];
}

// ===== MFMA GEMM (layers 2,3): C[M][NT](f16) = A[M][128] @ Bt[NT][128]^T =====
// R15: 1-D grid, n-tile fastest -> both n-tiles of a bx temporally adjacent (A reuse in L2/L3).
template<int NT>
__global__ __launch_bounds__(256, 3) void gemm_xlr(const _Float16* __restrict__ A,
                                                   const _Float16* __restrict__ Bt,
                                                   _Float16* __restrict__ C) {
    constexpr int NY = NT / 128;
    int bx = blockIdx.x / NY;
    int by = blockIdx.x % NY;
    int w = threadIdx.x >> 6, lane = threadIdx.x & 63;
    int m0 = bx * 128 + (w & 1) * 64;
    int n0 = by * 128 + (w >> 1) * 64;
    int q = lane >> 4, li = lane & 15;
    f32x4 acc[4][4] = {};
    const _Float16* Ap[4];
#pragma unroll
    for (int a = 0; a < 4; ++a) {
        int row = m0 + 16 * a + li;
        if (row > N_NODES - 1) row = N_NODES - 1;  // clamp: no OOB reads
        Ap[a] = A + (size_t)row * 128 + q * 8;
    }
    const _Float16* Bp = Bt + (size_t)(n0 + li) * 128 + q * 8;
#pragma unroll
    for (int kt = 0; kt < 4; ++kt) {
        v8h af[4], bf[4];
#pragma unroll
        for (int a = 0; a < 4; ++a) af[a] = *(const v8h*)(Ap[a] + kt * 32);
#pragma unroll
        for (int b = 0; b < 4; ++b) bf[b] = *(const v8h*)(Bp + (size_t)(16 * b) * 128 + kt * 32);
#pragma unroll
        for (int a = 0; a < 4; ++a)
#pragma unroll
            for (int b = 0; b < 4; ++b)
                acc[a][b] = __builtin_amdgcn_mfma_f32_16x16x32_f16(bf[b], af[a], acc[a][b], 0, 0, 0);
    }
#pragma unroll
    for (int a = 0; a < 4; ++a) {
        int m = m0 + 16 * a + li;
        if (m < N_NODES) {
#pragma unroll
            for (int b = 0; b < 4; ++b) {
                h4 t;
                t[0] = (_Float16)acc[a][b][0]; t[1] = (_Float16)acc[a][b][1];
                t[2] = (_Float16)acc[a][b][2]; t[3] = (_Float16)acc[a][b][3];
                *(h4*)(C + (size_t)m * NT + n0 + 16 * b + 4 * q) = t;
            }
        }
    }
}

// ========== fused GATv2: VEC=8, f32x2-packed, decoupled 2-level pipeline ==========
// R13: depth-2 clamped prefetch proven. R14: unclamped depth-3 regressed (+44MB FETCH).
// R15: the old "depth-2" was really depth-1: the row-load address depended on a csr-index
// load issued in the SAME iteration -> mid-iteration vmcnt drain every iteration.
// New structure: index pipeline 1 iter ahead of row pipeline; rows depth-3.
// Invariant at loop top (consuming position p):
//   ah0=row(p) ready, ah1=row(p+E), ah2=row(p+2E) in flight, si3=idx(p+3E) loaded.
// All prefetch positions clamped to [0, P-2] (re-reads own last row -> L1 hit, no extra
// FETCH) and src clamped to [0, N_NODES-1] (csr tail garbage-safe).
// VGPR ~32 -> ~42, still <= 64 -> 8 waves/EU occupancy preserved.
template<int HOUT, typename OUT_T>
__global__ __launch_bounds__(256, 8) void fused_gat(
    const _Float16* __restrict__ XLR,   // [N][2*HOUT] = [xl | xr]
    const int* __restrict__ off, const int* __restrict__ csr,
    const float* __restrict__ att, const float* __restrict__ bias,
    OUT_T* __restrict__ out) {          // [N][HOUT]
    constexpr int VEC = 8;
    constexpr int LPE = HOUT / VEC;     // lanes per edge (16 or 8)
    constexpr int EPW = 64 / LPE;       // edge groups per wave (4 or 8)
    constexpr int ST = 2 * HOUT;
    int wave = threadIdx.x >> 6, lane = threadIdx.x & 63;
    int node = blockIdx.x * (blockDim.x >> 6) + wave;
    if (node >= N_NODES) return;
    int g = lane / LPE;
    int lg = lane % LPE;
    int cb = lg * VEC;

    f32x2 at2[4], xr2[4];
#pragma unroll
    for (int j = 0; j < 4; ++j) { at2[j][0] = att[cb + 2 * j]; at2[j][1] = att[cb + 2 * j + 1]; }
    v8h xrh = *(const v8h*)(XLR + (size_t)node * ST + HOUT + cb);
    {
        const h2* x2 = (const h2*)&xrh;
#pragma unroll
        for (int j = 0; j < 4; ++j) { xr2[j][0] = (float)x2[j][0]; xr2[j][1] = (float)x2[j][1]; }
    }

    int eoff = off[node];
    int P = off[node + 1] - eoff + 1;   // position 0 = self-loop, 1..deg = csr edges
    float denom = 0.f;
    f32x2 acc2[4] = {};

    const int* cp = csr + eoff;
    const _Float16* Xcb = XLR + cb;
    int pmax_i = P - 2;                  // last valid csr index for this node

    // clamped csr index for position pos (pos >= 1): clamp(pos-1, 0, P-2)
    auto cidx = [&](int pos) -> int {
        int i = pos - 1;
        i = i > pmax_i ? pmax_i : i;
        return i < 0 ? 0 : i;
    };
    // clamped row load (src index garbage-safe)
    auto rowload = [&](int s) -> v8h {
        s = s < 0 ? 0 : s;
        s = s > N_NODES - 1 ? N_NODES - 1 : s;
        return *(const v8h*)(Xcb + (size_t)s * ST);
    };

    int p = g;
    // prologue: indices first (independent loads), then rows as they resolve
    int i1  = cp[cidx(p + EPW)];
    int i2  = cp[cidx(p + 2 * EPW)];
    int si3 = cp[cidx(p + 3 * EPW)];
    int s0  = (p == 0) ? node : cp[cidx(p)];
    v8h ah0 = rowload(s0);
    v8h ah1 = rowload(i1);
    v8h ah2 = rowload(i2);

    while (p < P) {
        v8h ch = ah0;
        ah0 = ah1;
        ah1 = ah2;
        ah2 = rowload(si3);              // address already resolved last iteration
        si3 = cp[cidx(p + 4 * EPW)];     // index for next iteration's row issue

        const h2* c2 = (const h2*)&ch;
        f32x2 a2[4];
        f32x2 sdot = {0.f, 0.f};
#pragma unroll
        for (int j = 0; j < 4; ++j) {
            a2[j][0] = (float)c2[j][0]; a2[j][1] = (float)c2[j][1];
            f32x2 v = a2[j] + xr2[j];
            f32x2 vn = v * NEG_SLOPE;
            f32x2 lv;
            lv[0] = fmaxf(v[0], vn[0]); lv[1] = fmaxf(v[1], vn[1]);
            sdot += at2[j] * lv;
        }
        float s = sdot[0] + sdot[1];
        s += __shfl_xor(s, 1); s += __shfl_xor(s, 2); s += __shfl_xor(s, 4);
        float f = __expf(s);
        denom += f;
        f32x2 f2 = {f, f};
#pragma unroll
        for (int j = 0; j < 4; ++j) acc2[j] += a2[j] * f2;   // v_pk_fma_f32
        p += EPW;
    }
#pragma unroll
    for (int o = LPE; o < 64; o <<= 1) {
#pragma unroll
        for (int j = 0; j < 4; ++j) {
            acc2[j][0] += __shfl_xor(acc2[j][0], o);
            acc2[j][1] += __shfl_xor(acc2[j][1], o);
        }
        denom += __shfl_xor(denom, o);
    }
    if (lane < LPE) {
        float inv = 1.f / denom;
        OUT_T* orow = out + (size_t)node * HOUT + cb;
#pragma unroll
        for (int j = 0; j < 4; ++j) {
#pragma unroll
            for (int t = 0; t < 2; ++t) {
                float r = acc2[j][t] * inv + bias[cb + 2 * j + t];
                r = r > 0.f ? r : (__expf(r) - 1.f);    // elu via fast exp
                orow[2 * j + t] = (OUT_T)r;
            }
        }
    }
}

extern "C" void kernel_launch(void* const* d_in, const int* in_sizes, int n_in,
                              void* d_out, int out_size, void* d_ws, size_t ws_size,
                              hipStream_t stream) {
    const float* x    = (const float*)d_in[0];
    const int*   ei   = (const int*)d_in[1];
    const int*   esrc = ei;
    const int*   edst = ei + N_EDGES;
    const float* W1l = (const float*)d_in[2];
    const float* W1r = (const float*)d_in[3];
    const float* att1= (const float*)d_in[4];
    const float* b1  = (const float*)d_in[5];
    const float* W2l = (const float*)d_in[6];
    const float* W2r = (const float*)d_in[7];
    const float* att2= (const float*)d_in[8];
    const float* b2  = (const float*)d_in[9];
    const float* W3l = (const float*)d_in[10];
    const float* W3r = (const float*)d_in[11];
    const float* att3= (const float*)d_in[12];
    const float* b3  = (const float*)d_in[13];
    float* out = (float*)d_out;

    // ---- workspace layout ----
    _Float16* XLR = (_Float16*)d_ws;                    // 50000*256
    _Float16* Hb  = XLR + (size_t)N_NODES * 256;        // 50000*128
    _Float16* Wt1 = Hb + (size_t)N_NODES * 128;         // 256*128
    _Float16* Wt2 = Wt1 + 256 * 128;                    // 256*128
    _Float16* Wt3 = Wt2 + 256 * 128;                    // 128*128
    int* bcnt = (int*)(Wt3 + 128 * 128);                // 512
    int* off  = bcnt + N_BKT;                           // 50001 (+1 pad)
    int* csr  = off + N_NODES + 1 + 1;                  // 800000
    int2* tmp = (int2*)(csr + N_EDGES);                 // N_BKT*BCAP int2 = 16.8 MB

    const int TB = 256;

    // ---- CSR build + weight prep; layer-1 GEMM merged with CSR finalize ----
    pack_weights_zero<<<cdiv(81920 + N_BKT, TB), TB, 0, stream>>>(
        W1l, W1r, W2l, W2r, W3l, W3r, Wt1, Wt2, Wt3, bcnt);
    bucket_scatter<<<cdiv(N_EDGES, CHUNK), 512, 0, stream>>>(esrc, edst, bcnt, tmp);
    csr_and_gemm1<<<NB_CSR + G1_BLOCKS, 256, 0, stream>>>(bcnt, tmp, off, csr, x, Wt1, XLR);

    const int WPB = 4;
    int gat_grid = cdiv(N_NODES, WPB);
    dim3 g2(cdiv(N_NODES, 128) * 2), g1(cdiv(N_NODES, 128));

    // ---- layer 1 ----
    fused_gat<128, _Float16><<<gat_grid, WPB * 64, 0, stream>>>(XLR, off, csr, att1, b1, Hb);
    // ---- layer 2 ----
    gemm_xlr<256><<<g2, 256, 0, stream>>>(Hb, Wt2, XLR);
    fused_gat<128, _Float16><<<gat_grid, WPB * 64, 0, stream>>>(XLR, off, csr, att2, b2, Hb);
    // ---- layer 3 ----
    gemm_xlr<128><<<g1, 256, 0, stream>>>(Hb, Wt3, XLR);
    fused_gat<64, float><<<gat_grid, WPB * 64, 0, stream>>>(XLR, off, csr, att3, b3, out);
}

// Round 2
// 280.427 us; speedup vs baseline: 1.0871x; 1.0300x over previous
//
#include <hip/hip_runtime.h>
#include <hip/hip_fp16.h>
#include <math.h>

#define N_NODES 50000
#define N_EDGES 800000
#define NEG_SLOPE 0.2f

#define BKT_SHIFT 7
#define N_BKT 512                      // pow2 upper bound; used: ceil(50000/128)=391
#define NB_CSR ((N_NODES + 127) / 128) // 391
#define CHUNK 2048                     // edges per phase-A block
#define BCAP 4096                      // fixed bucket capacity (mean 2048, 45 sigma)
#define PB_CAP 4096
#define G1_BLOCKS (((N_NODES + 127) / 128) * 2)   // 782 gemm-1 blocks (2 n-tiles)

typedef _Float16 v8h __attribute__((ext_vector_type(8)));
typedef _Float16 h4  __attribute__((ext_vector_type(4)));
typedef _Float16 h2  __attribute__((ext_vector_type(2)));
typedef float f32x4 __attribute__((ext_vector_type(4)));
typedef float f32x2 __attribute__((ext_vector_type(2)));

static inline int cdiv(long long a, int b) { return (int)((a + b - 1) / b); }

// R16: DPP-fused butterfly add step. Replaces __shfl_xor (ds_swizzle/bpermute = LDS
// round-trip + lgkmcnt wait) with a single VALU add reading the neighbor via DPP.
// CTRL: 0xB1 = quad_perm[1,0,3,2] (xor1), 0x4E = quad_perm[2,3,0,1] (xor2),
// 0x141 = row_half_mirror (lane i <-> 7-i within each 8-lane half: always crosses
// quads, never crosses the 8-lane head group -> completes the 8-lane sum).
template<int CTRL>
static __device__ __forceinline__ float dpp_xadd(float s) {
    int t = __builtin_amdgcn_mov_dpp(__builtin_bit_cast(int, s), CTRL, 0xf, 0xf, true);
    return s + __builtin_bit_cast(float, t);
}

// ========= weight packing W[K][N] f32 -> Wt[N][K] f16, plus bcnt zero-init =========
__global__ void pack_weights_zero(const float* __restrict__ W1l, const float* __restrict__ W1r,
                                  const float* __restrict__ W2l, const float* __restrict__ W2r,
                                  const float* __restrict__ W3l, const float* __restrict__ W3r,
                                  _Float16* __restrict__ Wt1, _Float16* __restrict__ Wt2,
                                  _Float16* __restrict__ Wt3, int* __restrict__ bcnt) {
    int id = blockIdx.x * blockDim.x + threadIdx.x;
    if (id < 32768) {                       // Wt1: [256][128]
        int n = id >> 7, k = id & 127;
        Wt1[id] = (_Float16)(n < 128 ? W1l[k * 128 + n] : W1r[k * 128 + n - 128]);
    } else if (id < 65536) {                // Wt2: [256][128]
        int j = id - 32768; int n = j >> 7, k = j & 127;
        Wt2[j] = (_Float16)(n < 128 ? W2l[k * 128 + n] : W2r[k * 128 + n - 128]);
    } else if (id < 81920) {                // Wt3: [128][128]
        int j = id - 65536; int n = j >> 7, k = j & 127;
        Wt3[j] = (_Float16)(n < 64 ? W3l[k * 64 + n] : W3r[k * 64 + n - 64]);
    } else if (id < 81920 + N_BKT) {
        bcnt[id - 81920] = 0;
    }
}

// ===== Phase A: LDS bucket sort per 2048-edge chunk, coalesced run append =====
__global__ __launch_bounds__(512) void bucket_scatter(const int* __restrict__ esrc,
                                                      const int* __restrict__ edst,
                                                      int* __restrict__ bcnt,
                                                      int2* __restrict__ tmp) {
    __shared__ int lhist[N_BKT];
    __shared__ int lscan[N_BKT];
    __shared__ int lofs[N_BKT];
    __shared__ int lcur[N_BKT];
    __shared__ int gbase[N_BKT];
    __shared__ int2 lpair[CHUNK];
    int tid = threadIdx.x;
    int base_e = blockIdx.x * CHUNK;
    int count = min(CHUNK, N_EDGES - base_e);

    if (tid < N_BKT) lhist[tid] = 0;
    __syncthreads();

    int e0 = base_e + tid * 4;
    int4 s4 = {0, 0, 0, 0}, d4 = {0, 0, 0, 0};
    int nmine = 0;
    if (e0 + 3 < N_EDGES && e0 + 3 < base_e + count) {
        s4 = *(const int4*)(esrc + e0);
        d4 = *(const int4*)(edst + e0);
        nmine = 4;
    } else if (e0 < N_EDGES) {
        nmine = min(N_EDGES - e0, 4);
        const int* sp = esrc + e0;
        const int* dp = edst + e0;
        if (nmine > 0) { s4.x = sp[0]; d4.x = dp[0]; }
        if (nmine > 1) { s4.y = sp[1]; d4.y = dp[1]; }
        if (nmine > 2) { s4.z = sp[2]; d4.z = dp[2]; }
    }
    int ds[4] = {d4.x, d4.y, d4.z, d4.w};
    int ss[4] = {s4.x, s4.y, s4.z, s4.w};
#pragma unroll
    for (int u = 0; u < 4; ++u)
        if (u < nmine) atomicAdd(&lhist[ds[u] >> BKT_SHIFT], 1);
    __syncthreads();

    // exclusive scan over N_BKT in LDS (Hillis-Steele, 512 threads = N_BKT)
    int v = lhist[tid];
    lscan[tid] = v;
    __syncthreads();
    for (int st = 1; st < N_BKT; st <<= 1) {
        int t = (tid >= st) ? lscan[tid - st] : 0;
        __syncthreads();
        lscan[tid] += t;
        __syncthreads();
    }
    {
        int excl = lscan[tid] - v;
        lofs[tid] = excl;
        lcur[tid] = excl;
        if (v > 0) gbase[tid] = tid * BCAP + atomicAdd(&bcnt[tid], v);
    }
    __syncthreads();

#pragma unroll
    for (int u = 0; u < 4; ++u)
        if (u < nmine) {
            int b = ds[u] >> BKT_SHIFT;
            int p = atomicAdd(&lcur[b], 1);
            lpair[p] = make_int2(ss[u], ds[u]);
        }
    __syncthreads();

    for (int j = tid; j < count; j += 512) {
        int2 pr = lpair[j];
        int b = pr.y >> BKT_SHIFT;
        int idx = gbase[b] + (j - lofs[b]);
        if (idx < (b + 1) * BCAP) tmp[idx] = pr;   // 45-sigma overflow guard
    }
}

// ===== Merged dispatch: blocks [0,391) finalize CSR; blocks [391, 391+782) run layer-1 GEMM =====
// R15: n-tile (by) fastest-varying so both n-tiles of a bx run temporally adjacent -> the
// f32 A rows (25.6MB) are read once from HBM, second read hits L2/L3.
__global__ __launch_bounds__(256, 2) void csr_and_gemm1(const int* __restrict__ bcnt,
                                                        const int2* __restrict__ tmp,
                                                        int* __restrict__ off,
                                                        int* __restrict__ csr,
                                                        const float* __restrict__ A,
                                                        const _Float16* __restrict__ Bt,
                                                        _Float16* __restrict__ C) {
    __shared__ int red[256];
    __shared__ int lcnt[128];
    __shared__ int sc[128];
    __shared__ int loff[129];
    __shared__ int lcur[128];
    __shared__ int lcsr[PB_CAP];
    int tid = threadIdx.x;

    if (blockIdx.x >= NB_CSR) {
        // ---------------- layer-1 GEMM part (A = f32 input, cast in-register) ------------
        int gb = blockIdx.x - NB_CSR;
        int bx = gb >> 1;               // R15: by fastest for A-row temporal reuse
        int by = gb & 1;                // 0 or 1
        int w = tid >> 6, lane = tid & 63;
        int m0 = bx * 128 + (w & 1) * 64;
        int n0 = by * 128 + (w >> 1) * 64;
        int q = lane >> 4, li = lane & 15;
        f32x4 acc[4][4] = {};
        const float* Ap[4];
#pragma unroll
        for (int a = 0; a < 4; ++a) {
            int row = m0 + 16 * a + li;
            if (row > N_NODES - 1) row = N_NODES - 1;
            Ap[a] = A + (size_t)row * 128 + q * 8;
        }
        const _Float16* Bp = Bt + (size_t)(n0 + li) * 128 + q * 8;
#pragma unroll
        for (int kt = 0; kt < 4; ++kt) {
            v8h af[4], bf[4];
#pragma unroll
            for (int a = 0; a < 4; ++a) {
                float4 lo = *(const float4*)(Ap[a] + kt * 32);
                float4 hi = *(const float4*)(Ap[a] + kt * 32 + 4);
                v8h t;
                t[0] = (_Float16)lo.x; t[1] = (_Float16)lo.y; t[2] = (_Float16)lo.z; t[3] = (_Float16)lo.w;
                t[4] = (_Float16)hi.x; t[5] = (_Float16)hi.y; t[6] = (_Float16)hi.z; t[7] = (_Float16)hi.w;
                af[a] = t;
            }
#pragma unroll
            for (int b = 0; b < 4; ++b) bf[b] = *(const v8h*)(Bp + (size_t)(16 * b) * 128 + kt * 32);
#pragma unroll
            for (int a = 0; a < 4; ++a)
#pragma unroll
                for (int b = 0; b < 4; ++b)
                    acc[a][b] = __builtin_amdgcn_mfma_f32_16x16x32_f16(bf[b], af[a], acc[a][b], 0, 0, 0);
        }
#pragma unroll
        for (int a = 0; a < 4; ++a) {
            int m = m0 + 16 * a + li;
            if (m < N_NODES) {
#pragma unroll
                for (int b = 0; b < 4; ++b) {
                    h4 t;
                    t[0] = (_Float16)acc[a][b][0]; t[1] = (_Float16)acc[a][b][1];
                    t[2] = (_Float16)acc[a][b][2]; t[3] = (_Float16)acc[a][b][3];
                    *(h4*)(C + (size_t)m * 256 + n0 + 16 * b + 4 * q) = t;
                }
            }
        }
        return;
    }

    // ---------------- CSR finalize part ----------------
    int b = blockIdx.x;
    int d0 = b << BKT_SHIFT;
    int dend = min(d0 + 128, N_NODES);
    int nn = dend - d0;

    int pre = 0;
    for (int i = tid; i < b; i += 256) pre += bcnt[i];
    red[tid] = pre;
    __syncthreads();
    for (int st = 128; st > 0; st >>= 1) {
        if (tid < st) red[tid] += red[tid + st];
        __syncthreads();
    }
    int base = red[0];
    __syncthreads();

    int n = min(bcnt[b], BCAP);
    int tbase = b * BCAP;

    if (tid < 128) lcnt[tid] = 0;
    __syncthreads();
    for (int j = tid; j < n; j += 256) {
        int dl = tmp[tbase + j].y - d0;
        atomicAdd(&lcnt[dl], 1);
    }
    __syncthreads();

    if (tid < 128) sc[tid] = lcnt[tid];
    __syncthreads();
    for (int st = 1; st < 128; st <<= 1) {
        int t = (tid < 128 && tid >= st) ? sc[tid - st] : 0;
        __syncthreads();
        if (tid < 128) sc[tid] += t;
        __syncthreads();
    }
    if (tid < 128) loff[tid + 1] = sc[tid];
    if (tid == 0) loff[0] = 0;
    if (tid < 128) lcur[tid] = 0;
    __syncthreads();

    if (tid < nn) off[d0 + tid] = base + loff[tid];
    if (tid == 0 && dend == N_NODES) off[N_NODES] = base + loff[nn];

    for (int j = tid; j < n; j += 256) {
        int2 pr = tmp[tbase + j];
        int dl = pr.y - d0;
        int r = atomicAdd(&lcur[dl], 1);
        int pos = loff[dl] + r;
        if (pos < PB_CAP) lcsr[pos] = pr.x;
    }
    __syncthreads();
    for (int j = tid; j < n; j += 256) csr[base + j] = lcsr[j];
}

// ===== MFMA GEMM (layers 2,3): C[M][NT](f16) = A[M][128] @ Bt[NT][128]^T =====
// R15: 1-D grid, n-tile fastest -> both n-tiles of a bx temporally adjacent (A reuse in L2/L3).
template<int NT>
__global__ __launch_bounds__(256, 3) void gemm_xlr(const _Float16* __restrict__ A,
                                                   const _Float16* __restrict__ Bt,
                                                   _Float16* __restrict__ C) {
    constexpr int NY = NT / 128;
    int bx = blockIdx.x / NY;
    int by = blockIdx.x % NY;
    int w = threadIdx.x >> 6, lane = threadIdx.x & 63;
    int m0 = bx * 128 + (w & 1) * 64;
    int n0 = by * 128 + (w >> 1) * 64;
    int q = lane >> 4, li = lane & 15;
    f32x4 acc[4][4] = {};
    const _Float16* Ap[4];
#pragma unroll
    for (int a = 0; a < 4; ++a) {
        int row = m0 + 16 * a + li;
        if (row > N_NODES - 1) row = N_NODES - 1;  // clamp: no OOB reads
        Ap[a] = A + (size_t)row * 128 + q * 8;
    }
    const _Float16* Bp = Bt + (size_t)(n0 + li) * 128 + q * 8;
#pragma unroll
    for (int kt = 0; kt < 4; ++kt) {
        v8h af[4], bf[4];
#pragma unroll
        for (int a = 0; a < 4; ++a) af[a] = *(const v8h*)(Ap[a] + kt * 32);
#pragma unroll
        for (int b = 0; b < 4; ++b) bf[b] = *(const v8h*)(Bp + (size_t)(16 * b) * 128 + kt * 32);
#pragma unroll
        for (int a = 0; a < 4; ++a)
#pragma unroll
            for (int b = 0; b < 4; ++b)
                acc[a][b] = __builtin_amdgcn_mfma_f32_16x16x32_f16(bf[b], af[a], acc[a][b], 0, 0, 0);
    }
#pragma unroll
    for (int a = 0; a < 4; ++a) {
        int m = m0 + 16 * a + li;
        if (m < N_NODES) {
#pragma unroll
            for (int b = 0; b < 4; ++b) {
                h4 t;
                t[0] = (_Float16)acc[a][b][0]; t[1] = (_Float16)acc[a][b][1];
                t[2] = (_Float16)acc[a][b][2]; t[3] = (_Float16)acc[a][b][3];
                *(h4*)(C + (size_t)m * NT + n0 + 16 * b + 4 * q) = t;
            }
        }
    }
}

// ========== fused GATv2: VEC=8, f32x2-packed, decoupled 2-level pipeline ==========
// R13: depth-2 clamped prefetch proven. R14: unclamped depth-3 regressed (+44MB FETCH).
// R15: decoupled index/row pipeline (rows depth-3, index 1 iter ahead) -> 52.5->43.3us.
// R16: (a) score reduction over 8 lanes via DPP-fused adds (quad_perm xor1, xor2,
//      row_half_mirror) instead of 3 dependent ds_swizzle/bpermute round-trips;
//      (b) att pre-scaled by log2e -> exp2f (native v_exp_f32, one fewer dependent mul);
//      (c) v_rcp for 1/denom (approx, once per node);
//      (d) WPB 4->2: finer block retirement granularity vs degree imbalance.
template<int HOUT, typename OUT_T>
__global__ __launch_bounds__(256, 8) void fused_gat(
    const _Float16* __restrict__ XLR,   // [N][2*HOUT] = [xl | xr]
    const int* __restrict__ off, const int* __restrict__ csr,
    const float* __restrict__ att, const float* __restrict__ bias,
    OUT_T* __restrict__ out) {          // [N][HOUT]
    constexpr int VEC = 8;
    constexpr int LPE = HOUT / VEC;     // lanes per edge (16 or 8)
    constexpr int EPW = 64 / LPE;       // edge groups per wave (4 or 8)
    constexpr int ST = 2 * HOUT;
    int wave = threadIdx.x >> 6, lane = threadIdx.x & 63;
    int node = blockIdx.x * (blockDim.x >> 6) + wave;
    if (node >= N_NODES) return;
    int g = lane / LPE;
    int lg = lane % LPE;
    int cb = lg * VEC;

    constexpr float LOG2E = 1.44269504088896340736f;
    f32x2 at2[4], xr2[4];
#pragma unroll
    for (int j = 0; j < 4; ++j) {
        at2[j][0] = att[cb + 2 * j] * LOG2E;       // R16: fold log2e -> exp2 domain
        at2[j][1] = att[cb + 2 * j + 1] * LOG2E;
    }
    v8h xrh = *(const v8h*)(XLR + (size_t)node * ST + HOUT + cb);
    {
        const h2* x2 = (const h2*)&xrh;
#pragma unroll
        for (int j = 0; j < 4; ++j) { xr2[j][0] = (float)x2[j][0]; xr2[j][1] = (float)x2[j][1]; }
    }

    int eoff = off[node];
    int P = off[node + 1] - eoff + 1;   // position 0 = self-loop, 1..deg = csr edges
    float denom = 0.f;
    f32x2 acc2[4] = {};

    const int* cp = csr + eoff;
    const _Float16* Xcb = XLR + cb;
    int pmax_i = P - 2;                  // last valid csr index for this node

    // clamped csr index for position pos (pos >= 1): clamp(pos-1, 0, P-2)
    auto cidx = [&](int pos) -> int {
        int i = pos - 1;
        i = i > pmax_i ? pmax_i : i;
        return i < 0 ? 0 : i;
    };
    // clamped row load (src index garbage-safe)
    auto rowload = [&](int s) -> v8h {
        s = s < 0 ? 0 : s;
        s = s > N_NODES - 1 ? N_NODES - 1 : s;
        return *(const v8h*)(Xcb + (size_t)s * ST);
    };

    int p = g;
    // prologue: indices first (independent loads), then rows as they resolve
    int i1  = cp[cidx(p + EPW)];
    int i2  = cp[cidx(p + 2 * EPW)];
    int si3 = cp[cidx(p + 3 * EPW)];
    int s0  = (p == 0) ? node : cp[cidx(p)];
    v8h ah0 = rowload(s0);
    v8h ah1 = rowload(i1);
    v8h ah2 = rowload(i2);

    while (p < P) {
        v8h ch = ah0;
        ah0 = ah1;
        ah1 = ah2;
        ah2 = rowload(si3);              // address already resolved last iteration
        si3 = cp[cidx(p + 4 * EPW)];     // index for next iteration's row issue

        const h2* c2 = (const h2*)&ch;
        f32x2 a2[4];
        f32x2 sdot = {0.f, 0.f};
#pragma unroll
        for (int j = 0; j < 4; ++j) {
            a2[j][0] = (float)c2[j][0]; a2[j][1] = (float)c2[j][1];
            f32x2 v = a2[j] + xr2[j];
            f32x2 vn = v * NEG_SLOPE;
            f32x2 lv;
            lv[0] = fmaxf(v[0], vn[0]); lv[1] = fmaxf(v[1], vn[1]);
            sdot += at2[j] * lv;
        }
        float s = sdot[0] + sdot[1];
        // R16: 8-lane sum via DPP adds (no LDS): xor1, xor2, then cross-quad mirror.
        s = dpp_xadd<0xB1>(s);           // quad_perm [1,0,3,2]
        s = dpp_xadd<0x4E>(s);           // quad_perm [2,3,0,1]
        s = dpp_xadd<0x141>(s);          // row_half_mirror: i <-> 7-i within 8
        float f = exp2f(s);              // att pre-scaled by log2e
        denom += f;
        f32x2 f2 = {f, f};
#pragma unroll
        for (int j = 0; j < 4; ++j) acc2[j] += a2[j] * f2;   // v_pk_fma_f32
        p += EPW;
    }
#pragma unroll
    for (int o = LPE; o < 64; o <<= 1) {
#pragma unroll
        for (int j = 0; j < 4; ++j) {
            acc2[j][0] += __shfl_xor(acc2[j][0], o);
            acc2[j][1] += __shfl_xor(acc2[j][1], o);
        }
        denom += __shfl_xor(denom, o);
    }
    if (lane < LPE) {
        float inv = __builtin_amdgcn_rcpf(denom);   // R16: approx rcp, once per node
        OUT_T* orow = out + (size_t)node * HOUT + cb;
#pragma unroll
        for (int j = 0; j < 4; ++j) {
#pragma unroll
            for (int t = 0; t < 2; ++t) {
                float r = acc2[j][t] * inv + bias[cb + 2 * j + t];
                r = r > 0.f ? r : (__expf(r) - 1.f);    // elu via fast exp
                orow[2 * j + t] = (OUT_T)r;
            }
        }
    }
}

extern "C" void kernel_launch(void* const* d_in, const int* in_sizes, int n_in,
                              void* d_out, int out_size, void* d_ws, size_t ws_size,
                              hipStream_t stream) {
    const float* x    = (const float*)d_in[0];
    const int*   ei   = (const int*)d_in[1];
    const int*   esrc = ei;
    const int*   edst = ei + N_EDGES;
    const float* W1l = (const float*)d_in[2];
    const float* W1r = (const float*)d_in[3];
    const float* att1= (const float*)d_in[4];
    const float* b1  = (const float*)d_in[5];
    const float* W2l = (const float*)d_in[6];
    const float* W2r = (const float*)d_in[7];
    const float* att2= (const float*)d_in[8];
    const float* b2  = (const float*)d_in[9];
    const float* W3l = (const float*)d_in[10];
    const float* W3r = (const float*)d_in[11];
    const float* att3= (const float*)d_in[12];
    const float* b3  = (const float*)d_in[13];
    float* out = (float*)d_out;

    // ---- workspace layout ----
    _Float16* XLR = (_Float16*)d_ws;                    // 50000*256
    _Float16* Hb  = XLR + (size_t)N_NODES * 256;        // 50000*128
    _Float16* Wt1 = Hb + (size_t)N_NODES * 128;         // 256*128
    _Float16* Wt2 = Wt1 + 256 * 128;                    // 256*128
    _Float16* Wt3 = Wt2 + 256 * 128;                    // 128*128
    int* bcnt = (int*)(Wt3 + 128 * 128);                // 512
    int* off  = bcnt + N_BKT;                           // 50001 (+1 pad)
    int* csr  = off + N_NODES + 1 + 1;                  // 800000
    int2* tmp = (int2*)(csr + N_EDGES);                 // N_BKT*BCAP int2 = 16.8 MB

    const int TB = 256;

    // ---- CSR build + weight prep; layer-1 GEMM merged with CSR finalize ----
    pack_weights_zero<<<cdiv(81920 + N_BKT, TB), TB, 0, stream>>>(
        W1l, W1r, W2l, W2r, W3l, W3r, Wt1, Wt2, Wt3, bcnt);
    bucket_scatter<<<cdiv(N_EDGES, CHUNK), 512, 0, stream>>>(esrc, edst, bcnt, tmp);
    csr_and_gemm1<<<NB_CSR + G1_BLOCKS, 256, 0, stream>>>(bcnt, tmp, off, csr, x, Wt1, XLR);

    const int WPB = 2;                  // R16: finer block retirement vs degree imbalance
    int gat_grid = cdiv(N_NODES, WPB);
    dim3 g2(cdiv(N_NODES, 128) * 2), g1(cdiv(N_NODES, 128));

    // ---- layer 1 ----
    fused_gat<128, _Float16><<<gat_grid, WPB * 64, 0, stream>>>(XLR, off, csr, att1, b1, Hb);
    // ---- layer 2 ----
    gemm_xlr<256><<<g2, 256, 0, stream>>>(Hb, Wt2, XLR);
    fused_gat<128, _Float16><<<gat_grid, WPB * 64, 0, stream>>>(XLR, off, csr, att2, b2, Hb);
    // ---- layer 3 ----
    gemm_xlr<128><<<g1, 256, 0, stream>>>(Hb, Wt3, XLR);
    fused_gat<64, float><<<gat_grid, WPB * 64, 0, stream>>>(XLR, off, csr, att3, b3, out);
}